// Round 5
// baseline (781.672 us; speedup 1.0000x reference)
//
#include <hip/hip_runtime.h>

#define KTAGS 64
#define START_TAG 1
#define END_TAG 2
#define NEGV -10000.0f
#define MAXT 512

// Broadcast lane i's register value to all lanes (no LDS, no barrier).
__device__ __forceinline__ float rl(float x, int i) {
  return __int_as_float(__builtin_amdgcn_readlane(__float_as_int(x), i));
}

// One Viterbi step for destination tag j (= lane): argmax_i ((tc[i]+feat)[+e]) + out[i].
// Exact float-add order of the reference; tree merge is exact because max +
// first-index tie-break over a fixed candidate set is order-independent
// (every merge takes the higher-index side only on strict >).
template<bool END>
__device__ __forceinline__ void step64(const float* tc, float feat, float e,
                                       float outj, float& best, int& besti) {
  float gv[8]; int gi[8];
#pragma unroll
  for (int g = 0; g < 8; ++g) {
    float c[8];
#pragma unroll
    for (int k = 0; k < 8; ++k) {
      const int i = g * 8 + k;
      float u = tc[i] + feat;
      if (END) u = u + e;
      c[k] = u + rl(outj, i);
    }
    float va = c[0]; int ia = 0;
    if (c[1] > va) { va = c[1]; ia = 1; }
    float vb = c[2]; int ib = 2;
    if (c[3] > vb) { vb = c[3]; ib = 3; }
    float vc = c[4]; int ic = 4;
    if (c[5] > vc) { vc = c[5]; ic = 5; }
    float vd = c[6]; int id = 6;
    if (c[7] > vd) { vd = c[7]; id = 7; }
    if (vb > va) { va = vb; ia = ib; }
    if (vd > vc) { vc = vd; ic = id; }
    if (vc > va) { va = vc; ia = ic; }
    gv[g] = va; gi[g] = g * 8 + ia;
  }
  if (gv[1] > gv[0]) { gv[0] = gv[1]; gi[0] = gi[1]; }
  if (gv[3] > gv[2]) { gv[2] = gv[3]; gi[2] = gi[3]; }
  if (gv[5] > gv[4]) { gv[4] = gv[5]; gi[4] = gi[5]; }
  if (gv[7] > gv[6]) { gv[6] = gv[7]; gi[6] = gi[7]; }
  if (gv[2] > gv[0]) { gv[0] = gv[2]; gi[0] = gi[2]; }
  if (gv[6] > gv[4]) { gv[4] = gv[6]; gi[4] = gi[6]; }
  if (gv[4] > gv[0]) { gv[0] = gv[4]; gi[0] = gi[4]; }
  best = gv[0]; besti = gi[0];
}

// Cross-lane argmax of final scores (first index wins ties), result uniform in all lanes.
__device__ __forceinline__ void final_argmax(float& v, int& idx) {
#pragma unroll
  for (int d = 1; d < 64; d <<= 1) {
    const float ov = __shfl_xor(v, d, 64);
    const int oi = __shfl_xor(idx, d, 64);
    if (ov > v || (ov == v && oi < idx)) { v = ov; idx = oi; }
  }
}

// ---------------- Variant A: backpointers in global workspace (high occupancy) -------------
// bp layout per block: row-group r = t>>2 occupies 256 B; byte for (t,j) at
// r*256 + j*4 + (t&3). Wave writes one packed dword per lane every 4 steps (256 B coalesced).
__global__ __launch_bounds__(64, 3) void crf_viterbi_ws(
    const float* __restrict__ feats, const int* __restrict__ leng,
    const float* __restrict__ trans, float* __restrict__ out_tags,
    float* __restrict__ out_scores, unsigned char* __restrict__ ws, int T) {
  const int b = blockIdx.x;
  const int j = threadIdx.x;

  __shared__ short s_tags[MAXT];

  const int L = leng[b];

  float tc[KTAGS];
#pragma unroll
  for (int i = 0; i < KTAGS; ++i) tc[i] = trans[i * KTAGS + j];

  float outj = (j == START_TAG) ? 0.0f : NEGV;

  const float* fp = feats + (size_t)b * T * KTAGS + j;
  unsigned char* bp = ws + (size_t)b * T * KTAGS;
  unsigned int* bp32 = (unsigned int*)bp;

  float feat_next = (L > 1) ? fp[1 * KTAGS] : 0.0f;
  unsigned int pk = 0;

  for (int t = 1; t < L - 1; ++t) {
    const float feat = feat_next;
    feat_next = fp[(t + 1) * KTAGS];  // prefetch next step
    float best; int bi;
    step64<false>(tc, feat, 0.0f, outj, best, bi);
    pk |= ((unsigned)bi) << ((t & 3) * 8);
    if ((t & 3) == 3) { bp32[(t >> 2) * KTAGS + j] = pk; pk = 0; }  // uniform branch
    outj = best;
  }
  if (L > 1) {  // last valid step: end_adj between (trans+feat) and (+out)
    const int t = L - 1;
    const float e = (j == END_TAG) ? 0.0f : NEGV;
    float best; int bi;
    step64<true>(tc, feat_next, e, outj, best, bi);
    pk |= ((unsigned)bi) << ((t & 3) * 8);
    bp32[(t >> 2) * KTAGS + j] = pk;  // flush (unused high bytes never read)
    outj = best;
  }

  float v = outj; int idx = j;
  final_argmax(v, idx);

  // Backtrace: chunks of 8 independent row loads (addresses depend only on s),
  // then a readlane-only dependent chain.
  int tag = idx;
  if (j == 0) s_tags[L - 1] = (short)tag;
  for (int s_hi = L - 1; s_hi >= 1; s_hi -= 8) {
    int rowv[8];
#pragma unroll
    for (int c = 0; c < 8; ++c) {
      const int s = s_hi - c;
      rowv[c] = (s >= 1) ? (int)bp[(s >> 2) * 256 + j * 4 + (s & 3)] : 0;
    }
#pragma unroll
    for (int c = 0; c < 8; ++c) {
      const int s = s_hi - c;
      if (s >= 1) {
        tag = __builtin_amdgcn_readlane(rowv[c], tag);
        if (j == 0) s_tags[s - 1] = (short)tag;
      }
    }
  }
  __syncthreads();

  for (int t = j; t < T; t += 64) {
    out_tags[(size_t)b * T + t] = (t < L) ? (float)s_tags[t] : 0.0f;
  }
  if (j == 0) out_scores[b] = v;
}

// ---------------- Variant B: LDS backpointers (fallback if ws too small) ----------------
__global__ __launch_bounds__(64) void crf_viterbi_lds(
    const float* __restrict__ feats, const int* __restrict__ leng,
    const float* __restrict__ trans, float* __restrict__ out_tags,
    float* __restrict__ out_scores, int T) {
  const int b = blockIdx.x;
  const int j = threadIdx.x;

  __shared__ unsigned char s_bp[MAXT * KTAGS];
  __shared__ short s_tags[MAXT];

  const int L = leng[b];

  float tc[KTAGS];
#pragma unroll
  for (int i = 0; i < KTAGS; ++i) tc[i] = trans[i * KTAGS + j];

  float outj = (j == START_TAG) ? 0.0f : NEGV;

  const float* fp = feats + (size_t)b * T * KTAGS + j;
  float feat_next = (L > 1) ? fp[1 * KTAGS] : 0.0f;

  for (int t = 1; t < L - 1; ++t) {
    const float feat = feat_next;
    feat_next = fp[(t + 1) * KTAGS];
    float best; int bi;
    step64<false>(tc, feat, 0.0f, outj, best, bi);
    s_bp[t * KTAGS + j] = (unsigned char)bi;
    outj = best;
  }
  if (L > 1) {
    const float e = (j == END_TAG) ? 0.0f : NEGV;
    float best; int bi;
    step64<true>(tc, feat_next, e, outj, best, bi);
    s_bp[(L - 1) * KTAGS + j] = (unsigned char)bi;
    outj = best;
  }

  float v = outj; int idx = j;
  final_argmax(v, idx);

  __syncthreads();

  int tag = idx;
  if (j == 0) s_tags[L - 1] = (short)tag;
  int row = (L > 1) ? (int)s_bp[(L - 1) * KTAGS + j] : 0;
  for (int t = L - 2; t >= 0; --t) {
    const int row_next = (t > 0) ? (int)s_bp[t * KTAGS + j] : 0;
    tag = __builtin_amdgcn_readlane(row, tag);
    if (j == 0) s_tags[t] = (short)tag;
    row = row_next;
  }
  __syncthreads();

  for (int t = j; t < T; t += 64) {
    out_tags[(size_t)b * T + t] = (t < L) ? (float)s_tags[t] : 0.0f;
  }
  if (j == 0) out_scores[b] = v;
}

extern "C" void kernel_launch(void* const* d_in, const int* in_sizes, int n_in,
                              void* d_out, int out_size, void* d_ws, size_t ws_size,
                              hipStream_t stream) {
  const float* feats = (const float*)d_in[0];
  const int* leng = (const int*)d_in[1];
  const float* trans = (const float*)d_in[2];
  const int B = in_sizes[1];
  const int T = in_sizes[0] / (B * KTAGS);  // 512

  float* out_tags = (float*)d_out;
  float* out_scores = out_tags + (size_t)B * T;

  const size_t need = (size_t)B * T * KTAGS;  // 64 MB backpointer workspace
  if (ws_size >= need) {
    crf_viterbi_ws<<<B, 64, 0, stream>>>(feats, leng, trans, out_tags, out_scores,
                                         (unsigned char*)d_ws, T);
  } else {
    crf_viterbi_lds<<<B, 64, 0, stream>>>(feats, leng, trans, out_tags, out_scores, T);
  }
}